// Round 1
// baseline (107.437 us; speedup 1.0000x reference)
//
#include <hip/hip_runtime.h>

// ---------------------------------------------------------------------------
// VisualContrastiveLoss on MI355X
// loss = C + mean_i log(Z_i) - mean_i sim[i, lab_i],  C = 1/0.07
//   Z_i = sum_j exp(sim_ij - C)  (fixed shift: dots bounded by 1)
//   sim = (f f^T)/0.07, f = row-normalized visual_feat
// R14: SYMMETRY — sim_ij = sim_ji, compute only tiles J >= I (2080/4096).
// R15: PIPELINE (T3/T4/T5) — remove the per-kk vmcnt(0)+__syncthreads drain:
//   * ldsA shrunk to 3 K-chunk planes (48KB); kk=3 A-frags live in regs
//     (32 VGPRs, loaded once per block with the exact frag-gather layout,
//     vmcnt forced pre-loop via dummy asm consume).
//   * ldsB double-buffered (2x16KB). Per kk: issue next B-chunk into the
//     other buffer -> s_waitcnt vmcnt(4) (own prev stage done, next in
//     flight) -> raw s_barrier (+sched_barrier/memory fences, rule 18) ->
//     frag reads + 16 MFMA wrapped in s_setprio(1/0) -> raw barrier.
//     vmcnt(0) only at the last chunk of the last J tile.
//   * next J's first B-chunk prefetched at kk=3 so its latency hides under
//     the exp2/Z epilogue; buffer-reuse barrier moved to loop bottom.
//   LDS total stays 80KB -> 2 blocks/CU preserved.
// Kept: A staged once (h() zero-conflict granule layout), FragU b128 frag
// loads, raw v_exp_f32, 3-kernel structure, grid(32,16) balance pairing.
// ---------------------------------------------------------------------------

typedef int i32x8 __attribute__((ext_vector_type(8)));
typedef float f32x4 __attribute__((ext_vector_type(4)));

#define B_N 8192
#define D_K 512
#define ROWB 512  // bytes per fp8 row
#define INVT 14.285714285714286f
// (1/0.07) * log2(e)
#define SCALE_LOG2 20.609929155556622f

#if defined(__has_builtin) && __has_builtin(__builtin_amdgcn_exp2f)
#define FAST_EXP2(x) __builtin_amdgcn_exp2f(x)
#else
#define FAST_EXP2(x) exp2f(x)
#endif

union FragU {
  int4 h[2];
  i32x8 v;
};

static __device__ __forceinline__ void load16_to_lds(const void* g, void* l) {
  __builtin_amdgcn_global_load_lds(
      (const __attribute__((address_space(1))) unsigned int*)g,
      (__attribute__((address_space(3))) unsigned int*)l, 16, 0, 0);
}

// Raw workgroup barrier WITHOUT the vmcnt(0) drain __syncthreads emits.
// Fenced on both sides (IR memory clobber + machine sched_barrier, rule 18).
static __device__ __forceinline__ void bar_nodrain() {
  __builtin_amdgcn_sched_barrier(0);
  asm volatile("" ::: "memory");
  __builtin_amdgcn_s_barrier();
  asm volatile("" ::: "memory");
  __builtin_amdgcn_sched_barrier(0);
}

#define VM_WAIT(N) asm volatile("s_waitcnt vmcnt(" #N ")" ::: "memory")

// ---- K1: 4 waves/block, one wave per row; normalize fp32 -> fp8 e4m3 --------
// Also zeroes Z (ws is poisoned before every launch).
__global__ __launch_bounds__(256)
void norm_kernel(const float* __restrict__ x,
                 unsigned char* __restrict__ fQ,
                 float* __restrict__ Z) {
  const int row = blockIdx.x * 4 + (threadIdx.x >> 6);
  const int lane = threadIdx.x & 63;
  const float4* xr = (const float4*)(x + (size_t)row * D_K);
  float4 a = xr[2 * lane];
  float4 b = xr[2 * lane + 1];
  float s = a.x * a.x + a.y * a.y + a.z * a.z + a.w * a.w +
            b.x * b.x + b.y * b.y + b.z * b.z + b.w * b.w;
#pragma unroll
  for (int off = 1; off < 64; off <<= 1) s += __shfl_xor(s, off);
  const float inv = 1.0f / fmaxf(sqrtf(s), 1e-12f);
  int lo = 0, hi = 0;
  lo = __builtin_amdgcn_cvt_pk_fp8_f32(a.x * inv, a.y * inv, lo, false);
  lo = __builtin_amdgcn_cvt_pk_fp8_f32(a.z * inv, a.w * inv, lo, true);
  hi = __builtin_amdgcn_cvt_pk_fp8_f32(b.x * inv, b.y * inv, hi, false);
  hi = __builtin_amdgcn_cvt_pk_fp8_f32(b.z * inv, b.w * inv, hi, true);
  int2 p; p.x = lo; p.y = hi;
  ((int2*)(fQ + (size_t)row * ROWB))[lane] = p;
  if (lane == 0) Z[row] = 0.0f;
}

// ---- K2: upper-triangular fp8 similarity + softmax-denominator --------------
// grid (32, 16): by<8 -> row band I=bx; by>=8 -> I=63-bx. Tile cols
// J in {J >= I, J == (by&7) mod 8}. 4 waves 2x2; wave owns 64x64 C via 4x4
// frags of 16x16x128 MX-fp8 MFMA (scale=1). Granule layout per 128B chunk:
// slot s of row r holds global granule h(s^(r&7)), h(u)=2(u&3)+(u>>2);
// frag reads at slots (q)^swz,(q+4)^swz -> granules 2q,2q+1, zero conflicts.
__global__ __launch_bounds__(256, 2)
void sim_kernel(const unsigned char* __restrict__ fQ,
                float* __restrict__ Z, float* __restrict__ T01,
                float* __restrict__ D) {
  __shared__ unsigned char ldsA[3 * 128 * 128];  // 48 KB: K-chunks 0..2
  __shared__ unsigned char ldsB[2 * 128 * 128];  // 32 KB: double-buffered B

  const int tid = threadIdx.x;
  const int lane = tid & 63;
  const int w = tid >> 6;
  const int wm = w & 1;       // wave row strip (0/1) -> rows wm*64..
  const int wn = w >> 1;      // wave col strip (0/1) -> cols wn*64..
  const int bx = blockIdx.x, by = blockIdx.y;
  const int b = by & 7;
  const int I = (by < 8) ? bx : (63 - bx);    // row band index
  const int Jfirst = I + ((b - I) & 7);       // first J >= I with J==b (mod 8)
  if (Jfirst > 63) return;                    // no tiles for this block
  const int I0 = I * 128;

  // staging lane geometry: 8 rows x 8 slots(16B) per instruction.
  const int srow = lane >> 3;                 // 0..7
  const int sb = lane & 7;                    // dest slot
  const int su = sb ^ srow;
  const int sg = 2 * (su & 3) + (su >> 2);    // source granule
  const size_t sOff = (size_t)srow * ROWB + sg * 16;  // bytes

  // fragment-read lane geometry
  const int fr = lane & 15;   // M/N index within 16
  const int q = lane >> 4;    // quad -> k chunk of 32B
  const int swz = fr & 7;     // row&7 of the frag row

  const int raRow = (wm * 64 + fr) * 128;
  const int rbRow = (wn * 64 + fr) * 128;
  const int off0 = (q ^ swz) * 16;        // slot holding granule 2q
  const int off1 = ((q + 4) ^ swz) * 16;  // slot holding granule 2q+1

  // ---- A chunk kk=3 -> registers, frag-layout-identical direct gather ------
  // LDS frag path yields row (wm*64+m*16+fr), bytes kk*128 + [q*32, q*32+32).
  FragU u3[4];
  {
    const unsigned char* aReg =
        fQ + (size_t)(I0 + wm * 64 + fr) * ROWB + 3 * 128 + q * 32;
#pragma unroll
    for (int m = 0; m < 4; ++m) {
      const unsigned char* p = aReg + (size_t)(m * 16) * ROWB;
      u3[m].h[0] = *(const int4*)(p);
      u3[m].h[1] = *(const int4*)(p + 16);
    }
  }
  // Force the vmcnt wait for u3 HERE (once, pre-pipeline) so the compiler
  // does not place a conservative vmcnt wait inside the K loop.
#pragma unroll
  for (int m = 0; m < 4; ++m) asm volatile("" ::"v"(u3[m].v));

  // ---- stage A once: planes kk=0..2; wave w stages rows w*32..+31 ----------
#pragma unroll
  for (int kk = 0; kk < 3; ++kk) {
    const unsigned char* gA = fQ + (size_t)(I0 + w * 32) * ROWB + kk * 128 + sOff;
    unsigned char* lA = ldsA + kk * (128 * 128) + (w * 32) * 128;
#pragma unroll
    for (int rr = 0; rr < 32; rr += 8)
      load16_to_lds(gA + (size_t)rr * ROWB, lA + rr * 128);
  }

  // ---- prologue: stage B(Jfirst, chunk 0) into buffer 0 --------------------
  int curOff = 0;  // active B buffer byte offset (0 / 16384)
  {
    const unsigned char* gB =
        fQ + (size_t)(Jfirst * 128 + w * 32) * ROWB + sOff;
    unsigned char* lB = ldsB + (w * 32) * 128;
#pragma unroll
    for (int rr = 0; rr < 32; rr += 8)
      load16_to_lds(gB + (size_t)rr * ROWB, lB + rr * 128);
  }

  float Zp[4][4];
#pragma unroll
  for (int m = 0; m < 4; ++m)
#pragma unroll
    for (int r = 0; r < 4; ++r) Zp[m][r] = 0.0f;

  f32x4 acc[4][4];

#pragma unroll 1
  for (int J = Jfirst; J < 64; J += 8) {
    const int J0 = J * 128;
#pragma unroll
    for (int m = 0; m < 4; ++m)
#pragma unroll
      for (int n = 0; n < 4; ++n) acc[m][n] = (f32x4){0.f, 0.f, 0.f, 0.f};

    // ---- kk = 0..2: A from LDS, B pipelined 1-deep -------------------------
#pragma unroll 1
    for (int kk = 0; kk < 3; ++kk) {
      {  // issue next B chunk (J, kk+1) into the other buffer
        const unsigned char* gB =
            fQ + (size_t)(J0 + w * 32) * ROWB + (kk + 1) * 128 + sOff;
        unsigned char* lB = ldsB + (curOff ^ 16384) + (w * 32) * 128;
#pragma unroll
        for (int rr = 0; rr < 32; rr += 8)
          load16_to_lds(gB + (size_t)rr * ROWB, lB + rr * 128);
      }
      // own previous stage (4 loads) retired; the 4 just issued stay in flight
      VM_WAIT(4);
      bar_nodrain();

      const unsigned char* raBase = ldsA + kk * (128 * 128) + raRow;
      const unsigned char* rbBase = ldsB + curOff + rbRow;
      i32x8 bv[4];
#pragma unroll
      for (int n = 0; n < 4; ++n) {
        const unsigned char* rb = rbBase + n * 16 * 128;
        FragU u;
        u.h[0] = *(const int4*)(rb + off0);
        u.h[1] = *(const int4*)(rb + off1);
        bv[n] = u.v;
      }
      __builtin_amdgcn_s_setprio(1);
#pragma unroll
      for (int mh = 0; mh < 2; ++mh) {  // m-split: av[2] live, not av[4]
        i32x8 av[2];
#pragma unroll
        for (int m = 0; m < 2; ++m) {
          const unsigned char* ra = raBase + (mh * 2 + m) * 16 * 128;
          FragU u;
          u.h[0] = *(const int4*)(ra + off0);
          u.h[1] = *(const int4*)(ra + off1);
          av[m] = u.v;
        }
#pragma unroll
        for (int m = 0; m < 2; ++m)
#pragma unroll
          for (int n = 0; n < 4; ++n)
            acc[mh * 2 + m][n] = __builtin_amdgcn_mfma_scale_f32_16x16x128_f8f6f4(
                av[m], bv[n], acc[mh * 2 + m][n], 0, 0, 0, 127, 0, 127);
      }
      __builtin_amdgcn_s_setprio(0);
      bar_nodrain();  // all waves done reading buf[cur] before its reuse
      curOff ^= 16384;
    }

    // ---- kk = 3: A from registers; prefetch next J's chunk 0 ---------------
    const bool hasNext = (J + 8) < 64;
    if (hasNext) {
      const unsigned char* gB =
          fQ + (size_t)((J + 8) * 128 + w * 32) * ROWB + sOff;
      unsigned char* lB = ldsB + (curOff ^ 16384) + (w * 32) * 128;
#pragma unroll
      for (int rr = 0; rr < 32; rr += 8)
        load16_to_lds(gB + (size_t)rr * ROWB, lB + rr * 128);
      VM_WAIT(4);
    } else {
      VM_WAIT(0);  // nothing issued beyond our own last stage: full drain
    }
    bar_nodrain();
    {
      const unsigned char* rbBase = ldsB + curOff + rbRow;
      i32x8 bv[4];
#pragma unroll
      for (int n = 0; n < 4; ++n) {
        const unsigned char* rb = rbBase + n * 16 * 128;
        FragU u;
        u.h[0] = *(const int4*)(rb + off0);
        u.h[1] = *(const int4*)(rb + off1);
        bv[n] = u.v;
      }
      __builtin_amdgcn_s_setprio(1);
#pragma unroll
      for (int m = 0; m < 4; ++m)
#pragma unroll
        for (int n = 0; n < 4; ++n)
          acc[m][n] = __builtin_amdgcn_mfma_scale_f32_16x16x128_f8f6f4(
              u3[m].v, bv[n], acc[m][n], 0, 0, 0, 127, 0, 127);
      __builtin_amdgcn_s_setprio(0);
    }
    curOff ^= 16384;
    // NOTE: buffer-reuse barrier deferred to loop bottom — the epilogue is
    // register/global-only, so waves drift through it independently while
    // the prefetched next-J chunk 0 is in flight.

    // T01: sim[0,c], sim[1,c] from rows 0,1 (band I==0 only)
    if (I == 0 && wm == 0) {
      if (q == 0) {
#pragma unroll
        for (int n = 0; n < 4; ++n) {
          const int col = J0 + wn * 64 + n * 16 + fr;
          T01[col * 2 + 0] = acc[0][n][0] * INVT;
          T01[col * 2 + 1] = acc[0][n][1] * INVT;
        }
      }
    }

    // D: diagonal dots, from the diagonal tile only
    if (J == I) {
#pragma unroll
      for (int m = 0; m < 4; ++m)
#pragma unroll
        for (int n = 0; n < 4; ++n) {
          const int col = J0 + wn * 64 + n * 16 + fr;
#pragma unroll
          for (int r = 0; r < 4; ++r) {
            const int row = I0 + wm * 64 + m * 16 + q * 4 + r;
            if (row == col) D[row] = acc[m][n][r];
          }
        }
    }

    // Z: row partials always; column sums for off-diag tiles (transpose
    // contribution to Z[J-band]).
    const bool offd = (J != I);
#pragma unroll
    for (int n = 0; n < 4; ++n) {
      float cs = 0.0f;
#pragma unroll
      for (int m = 0; m < 4; ++m)
#pragma unroll
        for (int r = 0; r < 4; ++r) {
          const float e = FAST_EXP2((acc[m][n][r] - 1.0f) * SCALE_LOG2);
          Zp[m][r] += e;
          cs += e;
        }
      if (offd) {
        cs += __shfl_xor(cs, 16);
        cs += __shfl_xor(cs, 32);
        if (q == 0) atomicAdd(&Z[J0 + wn * 64 + n * 16 + fr], cs);
      }
    }

    bar_nodrain();  // buf[cur] (just read at kk=3) may be restaged next iter
  }

  // row sums: reduce Zp across the 16 col-lanes, then atomicAdd
#pragma unroll
  for (int m = 0; m < 4; ++m)
#pragma unroll
    for (int r = 0; r < 4; ++r) {
      float v = Zp[m][r];
      v += __shfl_xor(v, 1);
      v += __shfl_xor(v, 2);
      v += __shfl_xor(v, 4);
      v += __shfl_xor(v, 8);
      if (fr == 0) atomicAdd(&Z[I0 + wm * 64 + m * 16 + q * 4 + r], v);
    }
}

// ---- K3: labels + exact-diagonal fixup + final loss reduction ---------------
// 1024 threads, 8 rows each, all loads batched/independent.
__global__ __launch_bounds__(1024)
void finalize_kernel(const float* __restrict__ Z,
                     const float* __restrict__ T01,
                     const float* __restrict__ D,
                     const int* __restrict__ ids,
                     const int* __restrict__ anchor,
                     float* __restrict__ out) {
  __shared__ float red[1024];
  const int t = threadIdx.x;
  const int anchor_id = ids[anchor[0]];
  const int sameLast = (ids[B_N - 1] == anchor_id);
  const int samePrev = (ids[B_N - 2] == anchor_id);
  int i[8], id[8];
  float z[8], d[8], t0[8], t1[8];
#pragma unroll
  for (int u = 0; u < 8; ++u) {
    i[u] = u * 1024 + t;
    z[u] = Z[i[u]];
    d[u] = D[i[u]];
    t0[u] = T01[i[u] * 2 + 0];
    t1[u] = T01[i[u] * 2 + 1];
    id[u] = ids[i[u]];
  }
  float sum = 0.0f;
#pragma unroll
  for (int u = 0; u < 8; ++u) {
    const int same_i = (id[u] == anchor_id);
    const int lab =
        (i[u] < B_N - 1) ? (same_i & sameLast) : (sameLast & samePrev);
    const float tt = lab ? t1[u] : t0[u];
    // replace quantized diag contribution with the exact value exp(0)=1
    const float Zc = z[u] - FAST_EXP2((d[u] - 1.0f) * SCALE_LOG2) + 1.0f;
    sum += tt - (INVT + logf(Zc));
  }
  red[t] = sum;
  __syncthreads();
  for (int off = 512; off > 0; off >>= 1) {
    if (t < off) red[t] += red[t + off];
    __syncthreads();
  }
  if (t == 0) out[0] = -red[0] / (float)B_N;
}

// ---------------------------------------------------------------------------
extern "C" void kernel_launch(void* const* d_in, const int* in_sizes, int n_in,
                              void* d_out, int out_size, void* d_ws, size_t ws_size,
                              hipStream_t stream) {
  const float* x = (const float*)d_in[0];
  const int* ids = (const int*)d_in[1];
  const int* anchor = (const int*)d_in[2];
  float* out = (float*)d_out;

  unsigned char* fQ = (unsigned char*)d_ws;                    // 4 MB fp8
  float* Z = (float*)((char*)d_ws + (size_t)B_N * ROWB);       // 32 KB
  float* T01 = Z + B_N;                                        // 64 KB
  float* D = T01 + 2 * B_N;                                    // 32 KB

  norm_kernel<<<B_N / 4, 256, 0, stream>>>(x, fQ, Z);
  sim_kernel<<<dim3(32, 16), 256, 0, stream>>>(fQ, Z, T01, D);
  finalize_kernel<<<1, 1024, 0, stream>>>(Z, T01, D, ids, anchor, out);
}